// Round 14
// baseline (322.722 us; speedup 1.0000x reference)
//
#include <hip/hip_runtime.h>

#define EPS 1e-5f

typedef __attribute__((ext_vector_type(8))) short short8v;
typedef __attribute__((ext_vector_type(4))) float f32x4;

__device__ __forceinline__ unsigned short f2bf(float f) {
    unsigned u = __builtin_bit_cast(unsigned, f);
    u += 0x7fffu + ((u >> 16) & 1u);
    return (unsigned short)(u >> 16);
}
__device__ __forceinline__ float bf2f(unsigned short h) {
    return __builtin_bit_cast(float, (unsigned)h << 16);
}

// ---------------- prep: zero summed+cnt AND convert x->bf16 ----------------
__global__ __launch_bounds__(256) void prep_kernel(const float* __restrict__ x,
                                                   unsigned short* __restrict__ xbf,
                                                   float* __restrict__ zbase,
                                                   long zn4, long n8) {
    long i = (long)blockIdx.x * blockDim.x + threadIdx.x;
    long stride = (long)gridDim.x * blockDim.x;
    float4* z4 = (float4*)zbase;
    for (long k = i; k < zn4; k += stride) z4[k] = make_float4(0.f, 0.f, 0.f, 0.f);
    const float4* x4 = (const float4*)x;
    for (long k = i; k < n8; k += stride) {
        float4 a = x4[2 * k], b = x4[2 * k + 1];
        short8v v;
        v[0] = (short)f2bf(a.x); v[1] = (short)f2bf(a.y);
        v[2] = (short)f2bf(a.z); v[3] = (short)f2bf(a.w);
        v[4] = (short)f2bf(b.x); v[5] = (short)f2bf(b.y);
        v[6] = (short)f2bf(b.z); v[7] = (short)f2bf(b.w);
        ((short8v*)xbf)[k] = v;
    }
}

// ---------------- histogram (must complete before mlp: provides offs/head) ----------------
__global__ __launch_bounds__(256) void hist_kernel(const int* __restrict__ col,
                                                   int* __restrict__ cnt, long E) {
    for (long e = (long)blockIdx.x * 256 + threadIdx.x; e < E; e += (long)gridDim.x * 256)
        atomicAdd(&cnt[col[e]], 1);
}

// ---------------- scans ----------------
__global__ __launch_bounds__(256) void scan1_kernel(const int* __restrict__ cnt,
                                                    int* __restrict__ offs,
                                                    int* __restrict__ partials, int N) {
    __shared__ int sdata[256];
    int t = threadIdx.x;
    int i0 = blockIdx.x * 1024 + t * 4;
    int c[4]; int tot = 0;
    #pragma unroll
    for (int j = 0; j < 4; ++j) { c[j] = (i0 + j < N) ? cnt[i0 + j] : 0; tot += c[j]; }
    sdata[t] = tot; __syncthreads();
    for (int d = 1; d < 256; d <<= 1) {
        int v = (t >= d) ? sdata[t - d] : 0;
        __syncthreads();
        sdata[t] += v;
        __syncthreads();
    }
    int run = sdata[t] - tot;
    #pragma unroll
    for (int j = 0; j < 4; ++j) { if (i0 + j < N) offs[i0 + j] = run; run += c[j]; }
    if (t == 255) partials[blockIdx.x] = sdata[255];
}

__global__ __launch_bounds__(256) void scan2_kernel(int* __restrict__ partials, int nb) {
    __shared__ int sdata[256];
    int t = threadIdx.x;
    int v = (t < nb) ? partials[t] : 0;
    sdata[t] = v; __syncthreads();
    for (int d = 1; d < 256; d <<= 1) {
        int w = (t >= d) ? sdata[t - d] : 0;
        __syncthreads();
        sdata[t] += w;
        __syncthreads();
    }
    if (t < nb) partials[t] = sdata[t] - v;
}

__global__ __launch_bounds__(256) void scan3_kernel(int* __restrict__ offs,
                                                    int* __restrict__ head,
                                                    const int* __restrict__ partials, int N) {
    int base = partials[blockIdx.x];
    int i0 = blockIdx.x * 1024 + threadIdx.x * 4;
    #pragma unroll
    for (int j = 0; j < 4; ++j) {
        int i = i0 + j;
        if (i < N) { int v = offs[i] + base; offs[i] = v; head[i] = v; }
    }
}

// ---------------- K1: natural-order mlp1 + LN -> m in DST-SORTED position ----------------
// Streams eattr sequentially; x-gather as before; slot from head atomic (replaces the
// old cnt atomic 1:1). Writes dsts[pos] for agg's segment detection. permscat eliminated.
__global__ __launch_bounds__(256) void mlp_kernel(
    const unsigned short* __restrict__ xbf, const int* __restrict__ eidx,
    const float* __restrict__ eattr,
    const float* __restrict__ W1, const float* __restrict__ b1,
    const float* __restrict__ g1, const float* __restrict__ be1,
    unsigned short* __restrict__ m, int* __restrict__ dsts,
    int* __restrict__ head, int E)
{
    const int lane = threadIdx.x & 63;
    const int wid  = threadIdx.x >> 6;
    const int c = lane & 15;
    const int q = lane >> 4;

    short8v w1f[4][4];
    #pragma unroll
    for (int ks = 0; ks < 4; ++ks)
        #pragma unroll
        for (int nt = 0; nt < 4; ++nt) {
            int k0 = ks * 32 + q * 8;
            int n  = nt * 16 + c;
            short8v f;
            #pragma unroll
            for (int j = 0; j < 8; ++j) f[j] = (short)f2bf(W1[(k0 + j) * 64 + n]);
            w1f[ks][nt] = f;
        }
    float b1v[4], g1v[4], bev[4];
    #pragma unroll
    for (int nt = 0; nt < 4; ++nt) {
        b1v[nt] = b1[nt * 16 + c];
        g1v[nt] = g1[nt * 16 + c];
        bev[nt] = be1[nt * 16 + c];
    }

    for (long e0 = (long)blockIdx.x * 256 + wid * 64; e0 < E; e0 += (long)gridDim.x * 256) {
        int sv_l, pos_l = 0;
        {
            long el = e0 + lane;
            sv_l = (el < E) ? eidx[el] : 0;
            if (el < E) {
                int cv = eidx[E + el];
                pos_l = atomicAdd(&head[cv], 1);
                dsts[pos_l] = cv;
            }
        }

        #pragma unroll
        for (int mt = 0; mt < 4; ++mt) {
            long er = e0 + mt * 16 + c;
            long ec = (er < E) ? er : (E - 1);
            int src = __shfl(sv_l, mt * 16 + c);
            const unsigned short* xp = xbf + (long)src * 64;
            const float* ep = eattr + ec * 64;

            f32x4 acc[4];
            #pragma unroll
            for (int nt = 0; nt < 4; ++nt) acc[nt] = (f32x4){0.f, 0.f, 0.f, 0.f};

            #pragma unroll
            for (int ks = 0; ks < 2; ++ks) {
                short8v a = *(const short8v*)(xp + ks * 32 + q * 8);
                #pragma unroll
                for (int nt = 0; nt < 4; ++nt)
                    acc[nt] = __builtin_amdgcn_mfma_f32_16x16x32_bf16(
                        a, w1f[ks][nt], acc[nt], 0, 0, 0);
            }
            #pragma unroll
            for (int ks = 2; ks < 4; ++ks) {
                int k0 = (ks - 2) * 32 + q * 8;
                float4 lo = *(const float4*)(ep + k0);
                float4 hi = *(const float4*)(ep + k0 + 4);
                short8v a;
                a[0] = (short)f2bf(lo.x); a[1] = (short)f2bf(lo.y);
                a[2] = (short)f2bf(lo.z); a[3] = (short)f2bf(lo.w);
                a[4] = (short)f2bf(hi.x); a[5] = (short)f2bf(hi.y);
                a[6] = (short)f2bf(hi.z); a[7] = (short)f2bf(hi.w);
                #pragma unroll
                for (int nt = 0; nt < 4; ++nt)
                    acc[nt] = __builtin_amdgcn_mfma_f32_16x16x32_bf16(
                        a, w1f[ks][nt], acc[nt], 0, 0, 0);
            }

            float s1[4] = {0, 0, 0, 0}, s2[4] = {0, 0, 0, 0};
            #pragma unroll
            for (int nt = 0; nt < 4; ++nt)
                #pragma unroll
                for (int r = 0; r < 4; ++r) {
                    float f = fmaxf(acc[nt][r] + b1v[nt], 0.f);
                    acc[nt][r] = f;
                    s1[r] += f; s2[r] += f * f;
                }
            #pragma unroll
            for (int mm = 1; mm <= 8; mm <<= 1)
                #pragma unroll
                for (int r = 0; r < 4; ++r) {
                    s1[r] += __shfl_xor(s1[r], mm);
                    s2[r] += __shfl_xor(s2[r], mm);
                }
            #pragma unroll
            for (int r = 0; r < 4; ++r) {
                float mu = s1[r] * (1.f / 64.f);
                float var = s2[r] * (1.f / 64.f) - mu * mu;
                float rs = rsqrtf(var + EPS);
                long ee = e0 + mt * 16 + q * 4 + r;
                int pos = __shfl(pos_l, mt * 16 + q * 4 + r);
                #pragma unroll
                for (int nt = 0; nt < 4; ++nt) {
                    float h = (acc[nt][r] - mu) * rs * g1v[nt] + bev[nt];
                    float nb = __shfl_xor(h, 1);
                    if (ee < E && !(c & 1)) {
                        unsigned pk = (unsigned)f2bf(h) | ((unsigned)f2bf(nb) << 16);
                        *(unsigned*)(m + (long)pos * 64 + nt * 16 + c) = pk;
                    }
                }
            }
        }
    }
}

// ---------------- K2: SEQUENTIAL slot-sweep aggregation; pk-atomic per segment ----------------
// m is already dst-sorted: no perm indirection, coalesced prefetchable row loads.
__global__ __launch_bounds__(256, 8) void agg_kernel(
    const unsigned short* __restrict__ m,
    const int* __restrict__ dsts, unsigned short* __restrict__ summed, int E)
{
    const int lane = threadIdx.x & 63;
    const int wid  = threadIdx.x >> 6;

    for (long s0 = ((long)blockIdx.x * 4 + wid) * 64; s0 < E; s0 += (long)gridDim.x * 256) {
        long sl = s0 + lane;
        int dv_l = (sl < E) ? dsts[sl] : -1;

        float acc = 0.f;
        #pragma unroll
        for (int base = 0; base < 64; base += 8) {
            int dv8[8]; float v[8];
            #pragma unroll
            for (int j = 0; j < 8; ++j) dv8[j] = __shfl(dv_l, base + j);
            int dvn = (base < 56) ? __shfl(dv_l, base + 8) : (int)0x80000000;
            #pragma unroll
            for (int j = 0; j < 8; ++j) {
                long slot = s0 + base + j;
                long sc = (slot < E) ? slot : 0;
                v[j] = bf2f(m[sc * 64 + lane]);
            }
            #pragma unroll
            for (int j = 0; j < 8; ++j) {
                if (dv8[j] >= 0) acc += v[j];
                int nxt = (j < 7) ? dv8[j + 1] : dvn;
                if (nxt != dv8[j]) {                 // wave-uniform branch
                    float nb = __shfl_xor(acc, 1);
                    if (dv8[j] >= 0 && !(lane & 1)) {
                        unsigned pk = (unsigned)f2bf(acc) | ((unsigned)f2bf(nb) << 16);
                        unsigned long long a64 = (unsigned long long)
                            (summed + (long)dv8[j] * 64 + lane);
                        asm volatile("global_atomic_pk_add_bf16 %0, %1, off"
                                     :: "v"(a64), "v"(pk));
                    }
                    acc = 0.f;
                }
            }
        }
    }
}

// ---------------- node stage (R10 proven version) ----------------
__global__ __launch_bounds__(256) void node_kernel(
    const float* __restrict__ x_h, const float* __restrict__ u,
    const float* __restrict__ W2, const float* __restrict__ b2,
    const float* __restrict__ g2, const float* __restrict__ be2,
    const float* __restrict__ W3, const float* __restrict__ b3,
    const float* __restrict__ g3, const float* __restrict__ be3,
    const unsigned short* __restrict__ summed, const int* __restrict__ cnt,
    float* __restrict__ out, int N)
{
    __shared__ unsigned short sh[4][64][72];

    const int lane = threadIdx.x & 63;
    const int wid  = threadIdx.x >> 6;
    const int c = lane & 15;
    const int q = lane >> 4;
    const float u0 = u[0];

    short8v w2f[4][4], w3f[2][4];
    #pragma unroll
    for (int ks = 0; ks < 4; ++ks)
        #pragma unroll
        for (int nt = 0; nt < 4; ++nt) {
            int k0 = ks * 32 + q * 8;
            int n  = nt * 16 + c;
            short8v f;
            #pragma unroll
            for (int j = 0; j < 8; ++j) f[j] = (short)f2bf(W2[(k0 + j) * 64 + n]);
            w2f[ks][nt] = f;
        }
    #pragma unroll
    for (int ks = 0; ks < 2; ++ks)
        #pragma unroll
        for (int nt = 0; nt < 4; ++nt) {
            int k0 = ks * 32 + q * 8;
            int n  = nt * 16 + c;
            short8v f;
            #pragma unroll
            for (int j = 0; j < 8; ++j) f[j] = (short)f2bf(W3[(k0 + j) * 64 + n]);
            w3f[ks][nt] = f;
        }

    float b2p[4], g2v[4], be2v[4], b3v[4], g3v[4], be3v[4];
    #pragma unroll
    for (int nt = 0; nt < 4; ++nt) {
        int n = nt * 16 + c;
        b2p[nt] = b2[n] + u0 * W2[128 * 64 + n];
        g2v[nt] = g2[n]; be2v[nt] = be2[n];
        b3v[nt] = b3[n]; g3v[nt] = g3[n]; be3v[nt] = be3[n];
    }

    const long n0 = ((long)blockIdx.x * 4 + wid) * 64;
    if (n0 >= N) return;

    #pragma unroll
    for (int mt = 0; mt < 4; ++mt) {
        long nr = n0 + mt * 16 + c;
        long nc = (nr < N) ? nr : (N - 1);
        const float* xp = x_h + nc * 64;
        const unsigned short* sp = summed + nc * 64;
        float inv = 1.f / fmaxf((float)cnt[nc], 1.f);

        f32x4 acc[4];
        #pragma unroll
        for (int nt = 0; nt < 4; ++nt) acc[nt] = (f32x4){0.f, 0.f, 0.f, 0.f};

        #pragma unroll
        for (int ks = 0; ks < 4; ++ks) {
            int k0 = ks * 32 + q * 8;
            short8v a;
            if (ks < 2) {
                float4 lo = *(const float4*)(xp + k0);
                float4 hi = *(const float4*)(xp + k0 + 4);
                a[0] = (short)f2bf(lo.x); a[1] = (short)f2bf(lo.y);
                a[2] = (short)f2bf(lo.z); a[3] = (short)f2bf(lo.w);
                a[4] = (short)f2bf(hi.x); a[5] = (short)f2bf(hi.y);
                a[6] = (short)f2bf(hi.z); a[7] = (short)f2bf(hi.w);
            } else {
                short8v raw = *(const short8v*)(sp + (k0 - 64));
                #pragma unroll
                for (int j = 0; j < 8; ++j)
                    a[j] = (short)f2bf(bf2f((unsigned short)raw[j]) * inv);
            }
            #pragma unroll
            for (int nt = 0; nt < 4; ++nt)
                acc[nt] = __builtin_amdgcn_mfma_f32_16x16x32_bf16(a, w2f[ks][nt], acc[nt], 0, 0, 0);
        }

        float s1[4] = {0, 0, 0, 0}, s2[4] = {0, 0, 0, 0};
        #pragma unroll
        for (int nt = 0; nt < 4; ++nt)
            #pragma unroll
            for (int r = 0; r < 4; ++r) {
                float f = fmaxf(acc[nt][r] + b2p[nt], 0.f);
                acc[nt][r] = f;
                s1[r] += f; s2[r] += f * f;
            }
        #pragma unroll
        for (int mm = 1; mm <= 8; mm <<= 1)
            #pragma unroll
            for (int r = 0; r < 4; ++r) {
                s1[r] += __shfl_xor(s1[r], mm);
                s2[r] += __shfl_xor(s2[r], mm);
            }
        #pragma unroll
        for (int r = 0; r < 4; ++r) {
            float mu = s1[r] * (1.f / 64.f);
            float var = s2[r] * (1.f / 64.f) - mu * mu;
            float rs = rsqrtf(var + EPS);
            #pragma unroll
            for (int nt = 0; nt < 4; ++nt) {
                float h2 = (acc[nt][r] - mu) * rs * g2v[nt] + be2v[nt];
                sh[wid][mt * 16 + q * 4 + r][nt * 16 + c] = f2bf(h2);
            }
        }
    }

    #pragma unroll
    for (int mt = 0; mt < 4; ++mt) {
        f32x4 acc[4];
        #pragma unroll
        for (int nt = 0; nt < 4; ++nt) acc[nt] = (f32x4){0.f, 0.f, 0.f, 0.f};

        #pragma unroll
        for (int ks = 0; ks < 2; ++ks) {
            short8v a = *(const short8v*)&sh[wid][mt * 16 + c][ks * 32 + q * 8];
            #pragma unroll
            for (int nt = 0; nt < 4; ++nt)
                acc[nt] = __builtin_amdgcn_mfma_f32_16x16x32_bf16(a, w3f[ks][nt], acc[nt], 0, 0, 0);
        }

        float s1[4] = {0, 0, 0, 0}, s2[4] = {0, 0, 0, 0};
        #pragma unroll
        for (int nt = 0; nt < 4; ++nt)
            #pragma unroll
            for (int r = 0; r < 4; ++r) {
                float f = acc[nt][r] + b3v[nt];
                acc[nt][r] = f;
                s1[r] += f; s2[r] += f * f;
            }
        #pragma unroll
        for (int mm = 1; mm <= 8; mm <<= 1)
            #pragma unroll
            for (int r = 0; r < 4; ++r) {
                s1[r] += __shfl_xor(s1[r], mm);
                s2[r] += __shfl_xor(s2[r], mm);
            }
        #pragma unroll
        for (int r = 0; r < 4; ++r) {
            float mu = s1[r] * (1.f / 64.f);
            float var = s2[r] * (1.f / 64.f) - mu * mu;
            float rs = rsqrtf(var + EPS);
            long node = n0 + mt * 16 + q * 4 + r;
            if (node < N) {
                #pragma unroll
                for (int nt = 0; nt < 4; ++nt) {
                    long off = node * 64 + nt * 16 + c;
                    float h3 = (acc[nt][r] - mu) * rs * g3v[nt] + be3v[nt];
                    out[off] = h3 + x_h[off];
                }
            }
        }
    }
}

extern "C" void kernel_launch(void* const* d_in, const int* in_sizes, int n_in,
                              void* d_out, int out_size, void* d_ws, size_t ws_size,
                              hipStream_t stream)
{
    const float* x_h   = (const float*)d_in[0];
    const int*   eidx  = (const int*)  d_in[1];
    const float* eattr = (const float*)d_in[2];
    const float* u     = (const float*)d_in[3];
    // d_in[4] = batch (all zeros, B=1) -> unused
    const float* W1  = (const float*)d_in[5];
    const float* b1  = (const float*)d_in[6];
    const float* g1  = (const float*)d_in[7];
    const float* be1 = (const float*)d_in[8];
    const float* W2  = (const float*)d_in[9];
    const float* b2  = (const float*)d_in[10];
    const float* g2  = (const float*)d_in[11];
    const float* be2 = (const float*)d_in[12];
    const float* W3  = (const float*)d_in[13];
    const float* b3  = (const float*)d_in[14];
    const float* g3  = (const float*)d_in[15];
    const float* be3 = (const float*)d_in[16];

    const int N = in_sizes[0] / 64;
    const int E = in_sizes[1] / 2;
    const int* col = eidx + E;

    // ws: xbf[N*128B] | summed[N*128B] | cnt[N*4] | offs[N*4] | head[N*4] | dsts[E*4] | m[E*128B] | partials
    char* w = (char*)d_ws;
    unsigned short* xbf    = (unsigned short*)w;   w += (size_t)N * 128;
    unsigned short* summed = (unsigned short*)w;   w += (size_t)N * 128;
    int* cnt      = (int*)w;                       w += (size_t)N * 4;
    int* offs     = (int*)w;                       w += (size_t)N * 4;
    int* head     = (int*)w;                       w += (size_t)N * 4;
    int* dsts     = (int*)w;                       w += (size_t)E * 4;
    unsigned short* m = (unsigned short*)w;        w += (size_t)E * 128;
    int* partials = (int*)w;

    // zero summed (N*32 f32) + cnt (N int) contiguous; convert x -> bf16
    prep_kernel<<<1024, 256, 0, stream>>>(x_h, xbf, (float*)summed,
                                          ((long)N * 33) / 4, (long)N * 8);
    hist_kernel<<<2048, 256, 0, stream>>>(col, cnt, E);
    int sblocks = (N + 1023) / 1024;
    scan1_kernel<<<sblocks, 256, 0, stream>>>(cnt, offs, partials, N);
    scan2_kernel<<<1, 256, 0, stream>>>(partials, sblocks);
    scan3_kernel<<<sblocks, 256, 0, stream>>>(offs, head, partials, N);

    mlp_kernel<<<2048, 256, 0, stream>>>(xbf, eidx, eattr, W1, b1, g1, be1,
                                         m, dsts, head, E);
    agg_kernel<<<2048, 256, 0, stream>>>(m, dsts, summed, E);

    int nblocks = (N + 255) / 256;
    node_kernel<<<nblocks, 256, 0, stream>>>(x_h, u, W2, b2, g2, be2, W3, b3, g3, be3,
                                             summed, cnt, (float*)d_out, N);
}

// Round 15
// 307.835 us; speedup vs baseline: 1.0484x; 1.0484x over previous
//
#include <hip/hip_runtime.h>

#define EPS 1e-5f

typedef __attribute__((ext_vector_type(8))) short short8v;
typedef __attribute__((ext_vector_type(4))) float f32x4;

__device__ __forceinline__ unsigned short f2bf(float f) {
    unsigned u = __builtin_bit_cast(unsigned, f);
    u += 0x7fffu + ((u >> 16) & 1u);
    return (unsigned short)(u >> 16);
}
__device__ __forceinline__ float bf2f(unsigned short h) {
    return __builtin_bit_cast(float, (unsigned)h << 16);
}

// ---------------- prep: zero summed+cnt AND convert x->bf16 ----------------
__global__ __launch_bounds__(256) void prep_kernel(const float* __restrict__ x,
                                                   unsigned short* __restrict__ xbf,
                                                   float* __restrict__ zbase,
                                                   long zn4, long n8) {
    long i = (long)blockIdx.x * blockDim.x + threadIdx.x;
    long stride = (long)gridDim.x * blockDim.x;
    float4* z4 = (float4*)zbase;
    for (long k = i; k < zn4; k += stride) z4[k] = make_float4(0.f, 0.f, 0.f, 0.f);
    const float4* x4 = (const float4*)x;
    for (long k = i; k < n8; k += stride) {
        float4 a = x4[2 * k], b = x4[2 * k + 1];
        short8v v;
        v[0] = (short)f2bf(a.x); v[1] = (short)f2bf(a.y);
        v[2] = (short)f2bf(a.z); v[3] = (short)f2bf(a.w);
        v[4] = (short)f2bf(b.x); v[5] = (short)f2bf(b.y);
        v[6] = (short)f2bf(b.z); v[7] = (short)f2bf(b.w);
        ((short8v*)xbf)[k] = v;
    }
}

// ---------------- histogram ----------------
__global__ __launch_bounds__(256) void hist_kernel(const int* __restrict__ col,
                                                   int* __restrict__ cnt, long E) {
    for (long e = (long)blockIdx.x * 256 + threadIdx.x; e < E; e += (long)gridDim.x * 256)
        atomicAdd(&cnt[col[e]], 1);
}

// ---------------- scans ----------------
__global__ __launch_bounds__(256) void scan1_kernel(const int* __restrict__ cnt,
                                                    int* __restrict__ offs,
                                                    int* __restrict__ partials, int N) {
    __shared__ int sdata[256];
    int t = threadIdx.x;
    int i0 = blockIdx.x * 1024 + t * 4;
    int c[4]; int tot = 0;
    #pragma unroll
    for (int j = 0; j < 4; ++j) { c[j] = (i0 + j < N) ? cnt[i0 + j] : 0; tot += c[j]; }
    sdata[t] = tot; __syncthreads();
    for (int d = 1; d < 256; d <<= 1) {
        int v = (t >= d) ? sdata[t - d] : 0;
        __syncthreads();
        sdata[t] += v;
        __syncthreads();
    }
    int run = sdata[t] - tot;
    #pragma unroll
    for (int j = 0; j < 4; ++j) { if (i0 + j < N) offs[i0 + j] = run; run += c[j]; }
    if (t == 255) partials[blockIdx.x] = sdata[255];
}

__global__ __launch_bounds__(256) void scan2_kernel(int* __restrict__ partials, int nb) {
    __shared__ int sdata[256];
    int t = threadIdx.x;
    int v = (t < nb) ? partials[t] : 0;
    sdata[t] = v; __syncthreads();
    for (int d = 1; d < 256; d <<= 1) {
        int w = (t >= d) ? sdata[t - d] : 0;
        __syncthreads();
        sdata[t] += w;
        __syncthreads();
    }
    if (t < nb) partials[t] = sdata[t] - v;
}

__global__ __launch_bounds__(256) void scan3_kernel(int* __restrict__ offs,
                                                    int* __restrict__ head,
                                                    const int* __restrict__ partials, int N) {
    int base = partials[blockIdx.x];
    int i0 = blockIdx.x * 1024 + threadIdx.x * 4;
    #pragma unroll
    for (int j = 0; j < 4; ++j) {
        int i = i0 + j;
        if (i < N) { int v = offs[i] + base; offs[i] = v; head[i] = v; }
    }
}

// ---------------- dsts fill: dsts[offs[i] .. offs[i]+cnt[i]) = i (sequential write) ----------------
__global__ __launch_bounds__(256) void dstfill_kernel(const int* __restrict__ offs,
                                                      const int* __restrict__ cnt,
                                                      int* __restrict__ dsts, int N) {
    for (int i = blockIdx.x * 256 + threadIdx.x; i < N; i += gridDim.x * 256) {
        int b = offs[i], c = cnt[i];
        for (int s = 0; s < c; ++s) dsts[b + s] = i;
    }
}

// ---------------- K1: natural-order mlp1 + LN -> m in DST-SORTED position ----------------
// Streams eattr sequentially; slot from head atomic; dsts now filled separately (no
// scattered 4B stores -> no partial-line writeback traffic).
__global__ __launch_bounds__(256) void mlp_kernel(
    const unsigned short* __restrict__ xbf, const int* __restrict__ eidx,
    const float* __restrict__ eattr,
    const float* __restrict__ W1, const float* __restrict__ b1,
    const float* __restrict__ g1, const float* __restrict__ be1,
    unsigned short* __restrict__ m, int* __restrict__ head, int E)
{
    const int lane = threadIdx.x & 63;
    const int wid  = threadIdx.x >> 6;
    const int c = lane & 15;
    const int q = lane >> 4;

    short8v w1f[4][4];
    #pragma unroll
    for (int ks = 0; ks < 4; ++ks)
        #pragma unroll
        for (int nt = 0; nt < 4; ++nt) {
            int k0 = ks * 32 + q * 8;
            int n  = nt * 16 + c;
            short8v f;
            #pragma unroll
            for (int j = 0; j < 8; ++j) f[j] = (short)f2bf(W1[(k0 + j) * 64 + n]);
            w1f[ks][nt] = f;
        }
    float b1v[4], g1v[4], bev[4];
    #pragma unroll
    for (int nt = 0; nt < 4; ++nt) {
        b1v[nt] = b1[nt * 16 + c];
        g1v[nt] = g1[nt * 16 + c];
        bev[nt] = be1[nt * 16 + c];
    }

    for (long e0 = (long)blockIdx.x * 256 + wid * 64; e0 < E; e0 += (long)gridDim.x * 256) {
        int sv_l, pos_l = 0;
        {
            long el = e0 + lane;
            sv_l = (el < E) ? eidx[el] : 0;
            if (el < E) pos_l = atomicAdd(&head[eidx[E + el]], 1);
        }

        #pragma unroll
        for (int mt = 0; mt < 4; ++mt) {
            long er = e0 + mt * 16 + c;
            long ec = (er < E) ? er : (E - 1);
            int src = __shfl(sv_l, mt * 16 + c);
            const unsigned short* xp = xbf + (long)src * 64;
            const float* ep = eattr + ec * 64;

            f32x4 acc[4];
            #pragma unroll
            for (int nt = 0; nt < 4; ++nt) acc[nt] = (f32x4){0.f, 0.f, 0.f, 0.f};

            #pragma unroll
            for (int ks = 0; ks < 2; ++ks) {
                short8v a = *(const short8v*)(xp + ks * 32 + q * 8);
                #pragma unroll
                for (int nt = 0; nt < 4; ++nt)
                    acc[nt] = __builtin_amdgcn_mfma_f32_16x16x32_bf16(
                        a, w1f[ks][nt], acc[nt], 0, 0, 0);
            }
            #pragma unroll
            for (int ks = 2; ks < 4; ++ks) {
                int k0 = (ks - 2) * 32 + q * 8;
                float4 lo = *(const float4*)(ep + k0);
                float4 hi = *(const float4*)(ep + k0 + 4);
                short8v a;
                a[0] = (short)f2bf(lo.x); a[1] = (short)f2bf(lo.y);
                a[2] = (short)f2bf(lo.z); a[3] = (short)f2bf(lo.w);
                a[4] = (short)f2bf(hi.x); a[5] = (short)f2bf(hi.y);
                a[6] = (short)f2bf(hi.z); a[7] = (short)f2bf(hi.w);
                #pragma unroll
                for (int nt = 0; nt < 4; ++nt)
                    acc[nt] = __builtin_amdgcn_mfma_f32_16x16x32_bf16(
                        a, w1f[ks][nt], acc[nt], 0, 0, 0);
            }

            float s1[4] = {0, 0, 0, 0}, s2[4] = {0, 0, 0, 0};
            #pragma unroll
            for (int nt = 0; nt < 4; ++nt)
                #pragma unroll
                for (int r = 0; r < 4; ++r) {
                    float f = fmaxf(acc[nt][r] + b1v[nt], 0.f);
                    acc[nt][r] = f;
                    s1[r] += f; s2[r] += f * f;
                }
            #pragma unroll
            for (int mm = 1; mm <= 8; mm <<= 1)
                #pragma unroll
                for (int r = 0; r < 4; ++r) {
                    s1[r] += __shfl_xor(s1[r], mm);
                    s2[r] += __shfl_xor(s2[r], mm);
                }
            #pragma unroll
            for (int r = 0; r < 4; ++r) {
                float mu = s1[r] * (1.f / 64.f);
                float var = s2[r] * (1.f / 64.f) - mu * mu;
                float rs = rsqrtf(var + EPS);
                long ee = e0 + mt * 16 + q * 4 + r;
                int pos = __shfl(pos_l, mt * 16 + q * 4 + r);
                #pragma unroll
                for (int nt = 0; nt < 4; ++nt) {
                    float h = (acc[nt][r] - mu) * rs * g1v[nt] + bev[nt];
                    float nb = __shfl_xor(h, 1);
                    if (ee < E && !(c & 1)) {
                        unsigned pk = (unsigned)f2bf(h) | ((unsigned)f2bf(nb) << 16);
                        *(unsigned*)(m + (long)pos * 64 + nt * 16 + c) = pk;
                    }
                }
            }
        }
    }
}

// ---------------- K2: SEQUENTIAL slot-sweep aggregation; pk-atomic per segment ----------------
__global__ __launch_bounds__(256, 8) void agg_kernel(
    const unsigned short* __restrict__ m,
    const int* __restrict__ dsts, unsigned short* __restrict__ summed, int E)
{
    const int lane = threadIdx.x & 63;
    const int wid  = threadIdx.x >> 6;

    for (long s0 = ((long)blockIdx.x * 4 + wid) * 64; s0 < E; s0 += (long)gridDim.x * 256) {
        long sl = s0 + lane;
        int dv_l = (sl < E) ? dsts[sl] : -1;

        float acc = 0.f;
        #pragma unroll
        for (int base = 0; base < 64; base += 8) {
            int dv8[8]; float v[8];
            #pragma unroll
            for (int j = 0; j < 8; ++j) dv8[j] = __shfl(dv_l, base + j);
            int dvn = (base < 56) ? __shfl(dv_l, base + 8) : (int)0x80000000;
            #pragma unroll
            for (int j = 0; j < 8; ++j) {
                long slot = s0 + base + j;
                long sc = (slot < E) ? slot : 0;
                v[j] = bf2f(m[sc * 64 + lane]);
            }
            #pragma unroll
            for (int j = 0; j < 8; ++j) {
                if (dv8[j] >= 0) acc += v[j];
                int nxt = (j < 7) ? dv8[j + 1] : dvn;
                if (nxt != dv8[j]) {                 // wave-uniform branch
                    float nb = __shfl_xor(acc, 1);
                    if (dv8[j] >= 0 && !(lane & 1)) {
                        unsigned pk = (unsigned)f2bf(acc) | ((unsigned)f2bf(nb) << 16);
                        unsigned long long a64 = (unsigned long long)
                            (summed + (long)dv8[j] * 64 + lane);
                        asm volatile("global_atomic_pk_add_bf16 %0, %1, off"
                                     :: "v"(a64), "v"(pk));
                    }
                    acc = 0.f;
                }
            }
        }
    }
}

// ---------------- node stage (R10 proven version) ----------------
__global__ __launch_bounds__(256) void node_kernel(
    const float* __restrict__ x_h, const float* __restrict__ u,
    const float* __restrict__ W2, const float* __restrict__ b2,
    const float* __restrict__ g2, const float* __restrict__ be2,
    const float* __restrict__ W3, const float* __restrict__ b3,
    const float* __restrict__ g3, const float* __restrict__ be3,
    const unsigned short* __restrict__ summed, const int* __restrict__ cnt,
    float* __restrict__ out, int N)
{
    __shared__ unsigned short sh[4][64][72];

    const int lane = threadIdx.x & 63;
    const int wid  = threadIdx.x >> 6;
    const int c = lane & 15;
    const int q = lane >> 4;
    const float u0 = u[0];

    short8v w2f[4][4], w3f[2][4];
    #pragma unroll
    for (int ks = 0; ks < 4; ++ks)
        #pragma unroll
        for (int nt = 0; nt < 4; ++nt) {
            int k0 = ks * 32 + q * 8;
            int n  = nt * 16 + c;
            short8v f;
            #pragma unroll
            for (int j = 0; j < 8; ++j) f[j] = (short)f2bf(W2[(k0 + j) * 64 + n]);
            w2f[ks][nt] = f;
        }
    #pragma unroll
    for (int ks = 0; ks < 2; ++ks)
        #pragma unroll
        for (int nt = 0; nt < 4; ++nt) {
            int k0 = ks * 32 + q * 8;
            int n  = nt * 16 + c;
            short8v f;
            #pragma unroll
            for (int j = 0; j < 8; ++j) f[j] = (short)f2bf(W3[(k0 + j) * 64 + n]);
            w3f[ks][nt] = f;
        }

    float b2p[4], g2v[4], be2v[4], b3v[4], g3v[4], be3v[4];
    #pragma unroll
    for (int nt = 0; nt < 4; ++nt) {
        int n = nt * 16 + c;
        b2p[nt] = b2[n] + u0 * W2[128 * 64 + n];
        g2v[nt] = g2[n]; be2v[nt] = be2[n];
        b3v[nt] = b3[n]; g3v[nt] = g3[n]; be3v[nt] = be3[n];
    }

    const long n0 = ((long)blockIdx.x * 4 + wid) * 64;
    if (n0 >= N) return;

    #pragma unroll
    for (int mt = 0; mt < 4; ++mt) {
        long nr = n0 + mt * 16 + c;
        long nc = (nr < N) ? nr : (N - 1);
        const float* xp = x_h + nc * 64;
        const unsigned short* sp = summed + nc * 64;
        float inv = 1.f / fmaxf((float)cnt[nc], 1.f);

        f32x4 acc[4];
        #pragma unroll
        for (int nt = 0; nt < 4; ++nt) acc[nt] = (f32x4){0.f, 0.f, 0.f, 0.f};

        #pragma unroll
        for (int ks = 0; ks < 4; ++ks) {
            int k0 = ks * 32 + q * 8;
            short8v a;
            if (ks < 2) {
                float4 lo = *(const float4*)(xp + k0);
                float4 hi = *(const float4*)(xp + k0 + 4);
                a[0] = (short)f2bf(lo.x); a[1] = (short)f2bf(lo.y);
                a[2] = (short)f2bf(lo.z); a[3] = (short)f2bf(lo.w);
                a[4] = (short)f2bf(hi.x); a[5] = (short)f2bf(hi.y);
                a[6] = (short)f2bf(hi.z); a[7] = (short)f2bf(hi.w);
            } else {
                short8v raw = *(const short8v*)(sp + (k0 - 64));
                #pragma unroll
                for (int j = 0; j < 8; ++j)
                    a[j] = (short)f2bf(bf2f((unsigned short)raw[j]) * inv);
            }
            #pragma unroll
            for (int nt = 0; nt < 4; ++nt)
                acc[nt] = __builtin_amdgcn_mfma_f32_16x16x32_bf16(a, w2f[ks][nt], acc[nt], 0, 0, 0);
        }

        float s1[4] = {0, 0, 0, 0}, s2[4] = {0, 0, 0, 0};
        #pragma unroll
        for (int nt = 0; nt < 4; ++nt)
            #pragma unroll
            for (int r = 0; r < 4; ++r) {
                float f = fmaxf(acc[nt][r] + b2p[nt], 0.f);
                acc[nt][r] = f;
                s1[r] += f; s2[r] += f * f;
            }
        #pragma unroll
        for (int mm = 1; mm <= 8; mm <<= 1)
            #pragma unroll
            for (int r = 0; r < 4; ++r) {
                s1[r] += __shfl_xor(s1[r], mm);
                s2[r] += __shfl_xor(s2[r], mm);
            }
        #pragma unroll
        for (int r = 0; r < 4; ++r) {
            float mu = s1[r] * (1.f / 64.f);
            float var = s2[r] * (1.f / 64.f) - mu * mu;
            float rs = rsqrtf(var + EPS);
            #pragma unroll
            for (int nt = 0; nt < 4; ++nt) {
                float h2 = (acc[nt][r] - mu) * rs * g2v[nt] + be2v[nt];
                sh[wid][mt * 16 + q * 4 + r][nt * 16 + c] = f2bf(h2);
            }
        }
    }

    #pragma unroll
    for (int mt = 0; mt < 4; ++mt) {
        f32x4 acc[4];
        #pragma unroll
        for (int nt = 0; nt < 4; ++nt) acc[nt] = (f32x4){0.f, 0.f, 0.f, 0.f};

        #pragma unroll
        for (int ks = 0; ks < 2; ++ks) {
            short8v a = *(const short8v*)&sh[wid][mt * 16 + c][ks * 32 + q * 8];
            #pragma unroll
            for (int nt = 0; nt < 4; ++nt)
                acc[nt] = __builtin_amdgcn_mfma_f32_16x16x32_bf16(a, w3f[ks][nt], acc[nt], 0, 0, 0);
        }

        float s1[4] = {0, 0, 0, 0}, s2[4] = {0, 0, 0, 0};
        #pragma unroll
        for (int nt = 0; nt < 4; ++nt)
            #pragma unroll
            for (int r = 0; r < 4; ++r) {
                float f = acc[nt][r] + b3v[nt];
                acc[nt][r] = f;
                s1[r] += f; s2[r] += f * f;
            }
        #pragma unroll
        for (int mm = 1; mm <= 8; mm <<= 1)
            #pragma unroll
            for (int r = 0; r < 4; ++r) {
                s1[r] += __shfl_xor(s1[r], mm);
                s2[r] += __shfl_xor(s2[r], mm);
            }
        #pragma unroll
        for (int r = 0; r < 4; ++r) {
            float mu = s1[r] * (1.f / 64.f);
            float var = s2[r] * (1.f / 64.f) - mu * mu;
            float rs = rsqrtf(var + EPS);
            long node = n0 + mt * 16 + q * 4 + r;
            if (node < N) {
                #pragma unroll
                for (int nt = 0; nt < 4; ++nt) {
                    long off = node * 64 + nt * 16 + c;
                    float h3 = (acc[nt][r] - mu) * rs * g3v[nt] + be3v[nt];
                    out[off] = h3 + x_h[off];
                }
            }
        }
    }
}

extern "C" void kernel_launch(void* const* d_in, const int* in_sizes, int n_in,
                              void* d_out, int out_size, void* d_ws, size_t ws_size,
                              hipStream_t stream)
{
    const float* x_h   = (const float*)d_in[0];
    const int*   eidx  = (const int*)  d_in[1];
    const float* eattr = (const float*)d_in[2];
    const float* u     = (const float*)d_in[3];
    // d_in[4] = batch (all zeros, B=1) -> unused
    const float* W1  = (const float*)d_in[5];
    const float* b1  = (const float*)d_in[6];
    const float* g1  = (const float*)d_in[7];
    const float* be1 = (const float*)d_in[8];
    const float* W2  = (const float*)d_in[9];
    const float* b2  = (const float*)d_in[10];
    const float* g2  = (const float*)d_in[11];
    const float* be2 = (const float*)d_in[12];
    const float* W3  = (const float*)d_in[13];
    const float* b3  = (const float*)d_in[14];
    const float* g3  = (const float*)d_in[15];
    const float* be3 = (const float*)d_in[16];

    const int N = in_sizes[0] / 64;
    const int E = in_sizes[1] / 2;
    const int* col = eidx + E;

    // ws: xbf[N*128B] | summed[N*128B] | cnt[N*4] | offs[N*4] | head[N*4] | dsts[E*4] | m[E*128B] | partials
    char* w = (char*)d_ws;
    unsigned short* xbf    = (unsigned short*)w;   w += (size_t)N * 128;
    unsigned short* summed = (unsigned short*)w;   w += (size_t)N * 128;
    int* cnt      = (int*)w;                       w += (size_t)N * 4;
    int* offs     = (int*)w;                       w += (size_t)N * 4;
    int* head     = (int*)w;                       w += (size_t)N * 4;
    int* dsts     = (int*)w;                       w += (size_t)E * 4;
    unsigned short* m = (unsigned short*)w;        w += (size_t)E * 128;
    int* partials = (int*)w;

    prep_kernel<<<1024, 256, 0, stream>>>(x_h, xbf, (float*)summed,
                                          ((long)N * 33) / 4, (long)N * 8);
    hist_kernel<<<2048, 256, 0, stream>>>(col, cnt, E);
    int sblocks = (N + 1023) / 1024;
    scan1_kernel<<<sblocks, 256, 0, stream>>>(cnt, offs, partials, N);
    scan2_kernel<<<1, 256, 0, stream>>>(partials, sblocks);
    scan3_kernel<<<sblocks, 256, 0, stream>>>(offs, head, partials, N);
    dstfill_kernel<<<512, 256, 0, stream>>>(offs, cnt, dsts, N);

    mlp_kernel<<<2048, 256, 0, stream>>>(xbf, eidx, eattr, W1, b1, g1, be1,
                                         m, head, E);
    agg_kernel<<<2048, 256, 0, stream>>>(m, dsts, summed, E);

    int nblocks = (N + 255) / 256;
    node_kernel<<<nblocks, 256, 0, stream>>>(x_h, u, W2, b2, g2, be2, W3, b3, g3, be3,
                                             summed, cnt, (float*)d_out, N);
}